// Round 13
// baseline (67.326 us; speedup 1.0000x reference)
//
#include <hip/hip_runtime.h>
#include <hip/hip_bf16.h>

#define BB 8
#define FF 4096
#define SS 1024
#define DD 128
#define DLL 256
#define NF (BB*FF)     // 32768 facts
#define NMSG (2*NF)    // 65536 message slots
#define NNODE (BB*SS)  // 8192 (b,s) rows
#define CAP 36         // bucket capacity per node

typedef short  short8 __attribute__((ext_vector_type(8)));
typedef float  f32x4  __attribute__((ext_vector_type(4)));

__device__ __forceinline__ uint f2bf(float x) {
    uint u = __float_as_uint(x);
    return (u + 0x7fffu + ((u >> 16) & 1u)) >> 16;
}
__device__ __forceinline__ float bf2f(uint lo16) {
    return __uint_as_float(lo16 << 16);
}

// gelu(x) = 0.5x(1+erf(x/sqrt2)); erf via A&S 7.1.26, |err|<=1.5e-7, branchless.
__device__ __forceinline__ float gelu_fast(float x) {
    const float z = fabsf(x) * 0.70710678118654752440f;
    const float t = __builtin_amdgcn_rcpf(__builtin_fmaf(0.3275911f, z, 1.0f));
    float p = 1.061405429f;
    p = __builtin_fmaf(p, t, -1.453152027f);
    p = __builtin_fmaf(p, t, 1.421413741f);
    p = __builtin_fmaf(p, t, -0.284496736f);
    p = __builtin_fmaf(p, t, 0.254829592f);
    p *= t;
    const float e = __expf(-z * z);
    const float erfv = __builtin_fmaf(-p, e, 1.0f);
    return 0.5f * x * (1.0f + copysignf(erfv, x));
}

// ---------------------------------------------------------------------------
// Zero kernel: cnt[NNODE] + pooled[BB*DD]
// ---------------------------------------------------------------------------
__global__ __launch_bounds__(256) void zero_kernel(int* __restrict__ cnt,
                                                   float* __restrict__ pooled)
{
    const int i = blockIdx.x * 256 + threadIdx.x;
    if (i < NNODE) { cnt[i] = 0; return; }
    const int j = i - NNODE;
    if (j < BB * DD) pooled[j] = 0.0f;
}

// ---------------------------------------------------------------------------
// Prep: table GEMMs Pa/Pc/PE (fp32 math, bf16 store), w2 frag-pack,
// packed bucket build.  Bucket entry = X | Y<<10 | rpi<<20.
// ---------------------------------------------------------------------------
#define N_W2 (256*128)
#define PA_BLOCKS 256                      // 4 s-rows per block
#define PE_BLOCK  PA_BLOCKS
#define FLAT0     (PA_BLOCKS + 1)
#define N_FLAT    (N_W2 + NMSG)
#define FLAT_BLOCKS ((N_FLAT + 255) / 256)  // 384
#define PREP_GRID (FLAT0 + FLAT_BLOCKS)

__global__ __launch_bounds__(256) void prep_kernel(
    const float* __restrict__ pos_emb, const float* __restrict__ pred_emb,
    const float* __restrict__ w1, const float* __restrict__ b1,
    const float* __restrict__ w2,
    const int* __restrict__ a0, const int* __restrict__ a1,
    const int* __restrict__ pidx, const float* __restrict__ bidir,
    ushort* __restrict__ Pa, ushort* __restrict__ Pc, ushort* __restrict__ PE,
    ushort* __restrict__ w2p, int* __restrict__ cnt, uint* __restrict__ idx32)
{
    const int blk = blockIdx.x;
    const int tid = threadIdx.x;

    if (blk < PA_BLOCKS) {
        __shared__ float ps[4][128];
        const int s0 = blk * 4;
        for (int q = tid; q < 512; q += 256) ps[q >> 7][q & 127] = pos_emb[s0 * 128 + q];
        __syncthreads();
        const int j = tid;
        float aa[4], ac[4];
        #pragma unroll
        for (int r = 0; r < 4; ++r) { aa[r] = 0.0f; ac[r] = 0.0f; }
        #pragma unroll 8
        for (int k = 0; k < 128; ++k) {
            const float wa = w1[k * 256 + j];
            const float wc = w1[(256 + k) * 256 + j];
            #pragma unroll
            for (int r = 0; r < 4; ++r) {
                aa[r] = __builtin_fmaf(ps[r][k], wa, aa[r]);
                ac[r] = __builtin_fmaf(ps[r][k], wc, ac[r]);
            }
        }
        #pragma unroll
        for (int r = 0; r < 4; ++r) {
            Pa[(s0 + r) * 256 + j] = (ushort)f2bf(aa[r]);
            Pc[(s0 + r) * 256 + j] = (ushort)f2bf(ac[r]);
        }
        return;
    }
    if (blk == PE_BLOCK) {
        __shared__ float pr[14][128];
        for (int q = tid; q < 14 * 128; q += 256) pr[q >> 7][q & 127] = pred_emb[q];
        __syncthreads();
        const int j = tid;
        float acc[14];
        #pragma unroll
        for (int r = 0; r < 14; ++r) acc[r] = 0.0f;
        #pragma unroll 8
        for (int k = 0; k < 128; ++k) {
            const float wb = w1[(128 + k) * 256 + j];
            #pragma unroll
            for (int r = 0; r < 14; ++r) acc[r] = __builtin_fmaf(pr[r][k], wb, acc[r]);
        }
        const float bj = b1[j];
        #pragma unroll
        for (int r = 0; r < 14; ++r) PE[r * 256 + j] = (ushort)f2bf(acc[r] + bj);
        return;
    }
    int i = (blk - FLAT0) * 256 + tid;
    if (i < N_W2) {   // i = k*128 + d -> frag-packed for GEMM2 A operand
        const int k = i >> 7, d = i & 127;
        const int d0 = d >> 4, lr = d & 15, ks = k >> 5, lq = (k >> 3) & 3, e = k & 7;
        w2p[(d0 * 8 + ks) * 512 + lr * 32 + lq * 8 + e] = (ushort)f2bf(w2[i]);
        return;
    }
    i -= N_W2;
    if (i < NMSG) {   // packed bucket build: msg slot i = fact*2 + parity
        const int g = i >> 1, p = i & 1;
        const float w = p ? bidir[g] : 1.0f;
        if (w != 0.0f) {
            const int ra0 = a0[g], ra1 = a1[g];
            const int X = p ? ra1 : ra0;       // through W1a
            const int Y = p ? ra0 : ra1;       // through W1c
            const int dest = p ? ra0 : ra1;    // destination node
            const int nid = ((g >> 12) << 10) + dest;
            const int slot = atomicAdd(&cnt[nid], 1);
            if (slot < CAP)
                idx32[nid * CAP + slot] = (uint)X | ((uint)Y << 10) | ((uint)pidx[g] << 20);
        }
    }
}

// ---------------------------------------------------------------------------
// node kernel: 16 nodes per 1024-thread block (1 node per wave, 16 waves).
// Phase1: G = sum gelu(Pa[X]+PE[pi]+Pc[Y]) fp32 regs, 2-msg unrolled.
// GEMM2 (waves 0-7) -> + c*b2 + pos_emb -> LN (all 16 waves) -> pooled.
// ---------------------------------------------------------------------------
__global__ __launch_bounds__(1024, 4) void node_kernel(
    const ushort* __restrict__ Pa, const ushort* __restrict__ Pc,
    const ushort* __restrict__ PE,
    const ushort* __restrict__ w2p, const float* __restrict__ b2,
    const float* __restrict__ pos_emb,
    const int* __restrict__ cnt, const uint* __restrict__ idx32,
    const float* __restrict__ ln_g, const float* __restrict__ ln_b,
    float* __restrict__ pooled)
{
    __shared__ uint4 h1g[512];        // 16 rows x 512 B, swizzled (8 KB)
    __shared__ float wsumS[16];
    __shared__ float aggf[16][132];   // padded fp32 agg tile (8.4 KB)
    __shared__ float red[16][128];    // pooled partials (8 KB)

    const int tid = threadIdx.x;
    const int wid = tid >> 6, lane = tid & 63;
    const int lq = lane >> 4, lr = lane & 15;
    const int nbase = blockIdx.x * 16;

    // ---- phase 1: one node per wave ----
    {
        const int n = wid;                   // local node 0..15
        const int nid = nbase + n;
        int c = cnt[nid]; if (c > CAP) c = CAP;
        const uint* bucket = idx32 + nid * CAP;
        float G0 = 0.0f, G1 = 0.0f, G2 = 0.0f, G3 = 0.0f;
        int j = 0;
        for (; j + 2 <= c; j += 2) {
            const uint e0 = bucket[j];
            const uint e1 = bucket[j + 1];
            const uint2 ua0 = *(const uint2*)(Pa + (e0 & 1023) * 256 + lane * 4);
            const uint2 ub0 = *(const uint2*)(PE + (e0 >> 20) * 256 + lane * 4);
            const uint2 uc0 = *(const uint2*)(Pc + ((e0 >> 10) & 1023) * 256 + lane * 4);
            const uint2 ua1 = *(const uint2*)(Pa + (e1 & 1023) * 256 + lane * 4);
            const uint2 ub1 = *(const uint2*)(PE + (e1 >> 20) * 256 + lane * 4);
            const uint2 uc1 = *(const uint2*)(Pc + ((e1 >> 10) & 1023) * 256 + lane * 4);
            G0 += gelu_fast(bf2f(ua0.x & 0xffffu) + bf2f(ub0.x & 0xffffu) + bf2f(uc0.x & 0xffffu))
                + gelu_fast(bf2f(ua1.x & 0xffffu) + bf2f(ub1.x & 0xffffu) + bf2f(uc1.x & 0xffffu));
            G1 += gelu_fast(bf2f(ua0.x >> 16) + bf2f(ub0.x >> 16) + bf2f(uc0.x >> 16))
                + gelu_fast(bf2f(ua1.x >> 16) + bf2f(ub1.x >> 16) + bf2f(uc1.x >> 16));
            G2 += gelu_fast(bf2f(ua0.y & 0xffffu) + bf2f(ub0.y & 0xffffu) + bf2f(uc0.y & 0xffffu))
                + gelu_fast(bf2f(ua1.y & 0xffffu) + bf2f(ub1.y & 0xffffu) + bf2f(uc1.y & 0xffffu));
            G3 += gelu_fast(bf2f(ua0.y >> 16) + bf2f(ub0.y >> 16) + bf2f(uc0.y >> 16))
                + gelu_fast(bf2f(ua1.y >> 16) + bf2f(ub1.y >> 16) + bf2f(uc1.y >> 16));
        }
        if (j < c) {
            const uint e = bucket[j];
            const uint2 ua = *(const uint2*)(Pa + (e & 1023) * 256 + lane * 4);
            const uint2 ub = *(const uint2*)(PE + (e >> 20) * 256 + lane * 4);
            const uint2 uc = *(const uint2*)(Pc + ((e >> 10) & 1023) * 256 + lane * 4);
            G0 += gelu_fast(bf2f(ua.x & 0xffffu) + bf2f(ub.x & 0xffffu) + bf2f(uc.x & 0xffffu));
            G1 += gelu_fast(bf2f(ua.x >> 16) + bf2f(ub.x >> 16) + bf2f(uc.x >> 16));
            G2 += gelu_fast(bf2f(ua.y & 0xffffu) + bf2f(ub.y & 0xffffu) + bf2f(uc.y & 0xffffu));
            G3 += gelu_fast(bf2f(ua.y >> 16) + bf2f(ub.y >> 16) + bf2f(uc.y >> 16));
        }
        uint2 t;
        t.x = f2bf(G0) | (f2bf(G1) << 16);
        t.y = f2bf(G2) | (f2bf(G3) << 16);
        const int col = lane * 8;     // byte col within 512B row
        const int byteoff = n * 512 + ((((col >> 4)) ^ (n & 15)) << 4) + (col & 15);
        *(uint2*)((char*)h1g + byteoff) = t;
        if (lane == 0) wsumS[n] = (float)c;
    }
    __syncthreads();

    // ---- GEMM2 (waves 0-7): D[d][m], m = lr, d = wid*16 + lq*4+r ----
    if (wid < 8) {
        f32x4 acc = (f32x4)0.0f;
        #pragma unroll
        for (int ks = 0; ks < 8; ++ks) {
            const int m = lr;
            const short8 hfrag = *(const short8*)((char*)h1g + m * 512 + ((((ks * 4 + lq)) ^ (m & 15)) << 4));
            const short8 wfrag = *(const short8*)(w2p + (wid * 8 + ks) * 512 + lr * 32 + lq * 8);
            acc = __builtin_amdgcn_mfma_f32_16x16x32_bf16(wfrag, hfrag, acc, 0, 0, 0);
        }
        // epilogue: + wsum*b2 + pos_emb -> aggf LDS
        const float wsm = wsumS[lr];
        const int s = (nbase + lr) & (SS - 1);
        const int d0 = wid * 16 + lq * 4;
        const float4 b24 = *(const float4*)(b2 + d0);
        const float4 pe4 = *(const float4*)(pos_emb + s * DD + d0);
        float4 o;
        o.x = __builtin_fmaf(wsm, b24.x, acc[0] + pe4.x);
        o.y = __builtin_fmaf(wsm, b24.y, acc[1] + pe4.y);
        o.z = __builtin_fmaf(wsm, b24.z, acc[2] + pe4.z);
        o.w = __builtin_fmaf(wsm, b24.w, acc[3] + pe4.w);
        *(float4*)&aggf[lr][d0] = o;
    }
    __syncthreads();

    // ---- LayerNorm + pool: one node per wave ----
    {
        const float g0 = ln_g[lane], g1 = ln_g[lane + 64];
        const float bb0 = ln_b[lane], bb1 = ln_b[lane + 64];
        const int n = wid;
        const float h0 = aggf[n][lane];
        const float h1 = aggf[n][lane + 64];
        float sum = h0 + h1;
        #pragma unroll
        for (int o = 32; o > 0; o >>= 1) sum += __shfl_xor(sum, o);
        const float mu = sum * (1.0f / 128.0f);
        const float d0 = h0 - mu, d1 = h1 - mu;
        float sq = d0 * d0 + d1 * d1;
        #pragma unroll
        for (int o = 32; o > 0; o >>= 1) sq += __shfl_xor(sq, o);
        const float rstd = rsqrtf(sq * (1.0f / 128.0f) + 1e-5f);
        red[wid][lane]      = d0 * rstd * g0 + bb0;
        red[wid][lane + 64] = d1 * rstd * g1 + bb1;
    }
    __syncthreads();
    if (tid < 128) {
        float v = 0.0f;
        #pragma unroll
        for (int w = 0; w < 16; ++w) v += red[w][tid];
        const int b = nbase >> 10;
        atomicAdd(&pooled[b * DD + tid], v);
    }
}

// ---------------------------------------------------------------------------
// Latent head
// ---------------------------------------------------------------------------
__global__ __launch_bounds__(256) void head_kernel(
    const float* __restrict__ pooled,
    const float* __restrict__ lw1, const float* __restrict__ lb1,
    const float* __restrict__ lw2, const float* __restrict__ lb2,
    float* __restrict__ out)
{
    const int b = blockIdx.x;
    const int j = threadIdx.x;
    __shared__ float p[128];
    __shared__ float t1[256];
    if (j < 128) p[j] = pooled[b*DD + j] * (1.0f / (float)SS);
    __syncthreads();
    float acc = lb1[j];
    #pragma unroll 8
    for (int k = 0; k < 128; ++k) acc = __builtin_fmaf(p[k], lw1[k * 256 + j], acc);
    t1[j] = gelu_fast(acc);
    __syncthreads();
    float acc2 = lb2[j];
    #pragma unroll 8
    for (int k = 0; k < 256; ++k) acc2 = __builtin_fmaf(t1[k], lw2[k * 256 + j], acc2);
    out[b*DLL + j] = acc2;
}

extern "C" void kernel_launch(void* const* d_in, const int* in_sizes, int n_in,
                              void* d_out, int out_size, void* d_ws, size_t ws_size,
                              hipStream_t stream) {
    const int*   a0       = (const int*)d_in[0];
    const int*   a1       = (const int*)d_in[1];
    const int*   pidx     = (const int*)d_in[2];
    const float* bidir    = (const float*)d_in[3];
    const float* pos_emb  = (const float*)d_in[4];
    const float* pred_emb = (const float*)d_in[5];
    const float* w1       = (const float*)d_in[6];
    const float* b1       = (const float*)d_in[7];
    const float* w2       = (const float*)d_in[8];
    const float* b2       = (const float*)d_in[9];
    const float* ln_g     = (const float*)d_in[10];
    const float* ln_b     = (const float*)d_in[11];
    const float* lw1      = (const float*)d_in[12];
    const float* lb1      = (const float*)d_in[13];
    const float* lw2      = (const float*)d_in[14];
    const float* lb2      = (const float*)d_in[15];

    char* ws = (char*)d_ws;
    const size_t O_CNT  = 0;                                // 32 KB (int[NNODE])
    const size_t O_POOL = 32768;                            // 4 KB  (fp32[B*D])
    const size_t O_IDX  = O_POOL + 4096;                    // 1.18 MB (NNODE*CAP u32)
    const size_t O_W2P  = O_IDX + (size_t)NNODE * CAP * 4;  // 64 KB
    const size_t O_PA   = O_W2P + 65536;                    // 512 KB
    const size_t O_PC   = O_PA + 524288;                    // 512 KB
    const size_t O_PE   = O_PC + 524288;                    // 7 KB

    int*    cnt    = (int*)(ws + O_CNT);
    float*  pooled = (float*)(ws + O_POOL);
    uint*   idx32  = (uint*)(ws + O_IDX);
    ushort* w2p    = (ushort*)(ws + O_W2P);
    ushort* Pa     = (ushort*)(ws + O_PA);
    ushort* Pc     = (ushort*)(ws + O_PC);
    ushort* PE     = (ushort*)(ws + O_PE);

    zero_kernel<<<(NNODE + BB*DD + 255) / 256, 256, 0, stream>>>(cnt, pooled);
    prep_kernel<<<PREP_GRID, 256, 0, stream>>>(
        pos_emb, pred_emb, w1, b1, w2, a0, a1, pidx, bidir,
        Pa, Pc, PE, w2p, cnt, idx32);
    node_kernel<<<NNODE / 16, 1024, 0, stream>>>(
        Pa, Pc, PE, w2p, b2, pos_emb, cnt, idx32, ln_g, ln_b, pooled);
    head_kernel<<<BB, 256, 0, stream>>>(pooled, lw1, lb1, lw2, lb2, (float*)d_out);
}

// Round 14
// 49.339 us; speedup vs baseline: 1.3646x; 1.3646x over previous
//
#include <hip/hip_runtime.h>
#include <hip/hip_bf16.h>

#define BB 8
#define FF 4096
#define SS 1024
#define DD 128
#define DLL 256
#define NF (BB*FF)     // 32768 facts
#define NMSG (2*NF)    // 65536 message slots
#define NNODE (BB*SS)  // 8192 (b,s) rows
#define CAP 36         // bucket capacity per node

typedef short  short8 __attribute__((ext_vector_type(8)));
typedef float  f32x4  __attribute__((ext_vector_type(4)));

__device__ __forceinline__ uint f2bf(float x) {
    uint u = __float_as_uint(x);
    return (u + 0x7fffu + ((u >> 16) & 1u)) >> 16;
}
__device__ __forceinline__ float bf2f(uint lo16) {
    return __uint_as_float(lo16 << 16);
}

// gelu(x) = 0.5x(1+erf(x/sqrt2)); erf via A&S 7.1.26, |err|<=1.5e-7, branchless.
__device__ __forceinline__ float gelu_fast(float x) {
    const float z = fabsf(x) * 0.70710678118654752440f;
    const float t = __builtin_amdgcn_rcpf(__builtin_fmaf(0.3275911f, z, 1.0f));
    float p = 1.061405429f;
    p = __builtin_fmaf(p, t, -1.453152027f);
    p = __builtin_fmaf(p, t, 1.421413741f);
    p = __builtin_fmaf(p, t, -0.284496736f);
    p = __builtin_fmaf(p, t, 0.254829592f);
    p *= t;
    const float e = __expf(-z * z);
    const float erfv = __builtin_fmaf(-p, e, 1.0f);
    return 0.5f * x * (1.0f + copysignf(erfv, x));
}

// ---------------------------------------------------------------------------
// Zero kernel: cnt[NNODE] + pooled[BB*DD]
// ---------------------------------------------------------------------------
__global__ __launch_bounds__(256) void zero_kernel(int* __restrict__ cnt,
                                                   float* __restrict__ pooled)
{
    const int i = blockIdx.x * 256 + threadIdx.x;
    if (i < NNODE) { cnt[i] = 0; return; }
    const int j = i - NNODE;
    if (j < BB * DD) pooled[j] = 0.0f;
}

// ---------------------------------------------------------------------------
// Prep: table GEMMs Pa/Pc (PA blocks) + PE (4 LDS-staged blocks; kills the
// single-block serial-load tail seen in rocprof: 42us @ 2.6% occupancy),
// w2 frag-pack, packed bucket build.  Bucket entry = X | Y<<10 | rpi<<20.
// ---------------------------------------------------------------------------
#define N_W2 (256*128)
#define PA_BLOCKS 256                      // 4 s-rows per block
#define PE0       PA_BLOCKS                // 4 PE blocks, 64 j-cols each
#define FLAT0     (PA_BLOCKS + 4)
#define N_FLAT    (N_W2 + NMSG)
#define FLAT_BLOCKS ((N_FLAT + 255) / 256)  // 384
#define PREP_GRID (FLAT0 + FLAT_BLOCKS)

__global__ __launch_bounds__(256) void prep_kernel(
    const float* __restrict__ pos_emb, const float* __restrict__ pred_emb,
    const float* __restrict__ w1, const float* __restrict__ b1,
    const float* __restrict__ w2,
    const int* __restrict__ a0, const int* __restrict__ a1,
    const int* __restrict__ pidx, const float* __restrict__ bidir,
    ushort* __restrict__ Pa, ushort* __restrict__ Pc, ushort* __restrict__ PE,
    ushort* __restrict__ w2p, int* __restrict__ cnt, uint* __restrict__ idx32)
{
    const int blk = blockIdx.x;
    const int tid = threadIdx.x;

    if (blk < PA_BLOCKS) {
        __shared__ float ps[4][128];
        const int s0 = blk * 4;
        for (int q = tid; q < 512; q += 256) ps[q >> 7][q & 127] = pos_emb[s0 * 128 + q];
        __syncthreads();
        const int j = tid;
        float aa[4], ac[4];
        #pragma unroll
        for (int r = 0; r < 4; ++r) { aa[r] = 0.0f; ac[r] = 0.0f; }
        #pragma unroll 4
        for (int k = 0; k < 128; ++k) {
            const float wa = w1[k * 256 + j];
            const float wc = w1[(256 + k) * 256 + j];
            #pragma unroll
            for (int r = 0; r < 4; ++r) {
                aa[r] = __builtin_fmaf(ps[r][k], wa, aa[r]);
                ac[r] = __builtin_fmaf(ps[r][k], wc, ac[r]);
            }
        }
        #pragma unroll
        for (int r = 0; r < 4; ++r) {
            Pa[(s0 + r) * 256 + j] = (ushort)f2bf(aa[r]);
            Pc[(s0 + r) * 256 + j] = (ushort)f2bf(ac[r]);
        }
        return;
    }
    if (blk < FLAT0) {
        // PE: 4 blocks, j-chunk of 64 cols each; w1b chunk + pred rows in LDS.
        __shared__ float w1s[128][64];    // 32 KB
        __shared__ float prs[16][128];    // 8 KB (rows 14/15 zeroed)
        const int j0 = (blk - PE0) * 64;
        for (int q = tid; q < 128 * 64; q += 256) {
            const int k = q >> 6, jj = q & 63;
            w1s[k][jj] = w1[(128 + k) * 256 + j0 + jj];
        }
        for (int q = tid; q < 16 * 128; q += 256)
            prs[q >> 7][q & 127] = (q < 14 * 128) ? pred_emb[q] : 0.0f;
        __syncthreads();
        const int jl = tid & 63, rq = tid >> 6;    // wave-uniform rq
        float acc[4] = {0.0f, 0.0f, 0.0f, 0.0f};
        #pragma unroll 8
        for (int k = 0; k < 128; ++k) {
            const float wv = w1s[k][jl];
            #pragma unroll
            for (int i = 0; i < 4; ++i)
                acc[i] = __builtin_fmaf(prs[rq + 4 * i][k], wv, acc[i]);
        }
        const float bj = b1[j0 + jl];
        #pragma unroll
        for (int i = 0; i < 4; ++i) {
            const int r = rq + 4 * i;
            if (r < 14) PE[r * 256 + j0 + jl] = (ushort)f2bf(acc[i] + bj);
        }
        return;
    }
    int i = (blk - FLAT0) * 256 + tid;
    if (i < N_W2) {   // i = k*128 + d -> frag-packed for GEMM2 A operand
        const int k = i >> 7, d = i & 127;
        const int d0 = d >> 4, lr = d & 15, ks = k >> 5, lq = (k >> 3) & 3, e = k & 7;
        w2p[(d0 * 8 + ks) * 512 + lr * 32 + lq * 8 + e] = (ushort)f2bf(w2[i]);
        return;
    }
    i -= N_W2;
    if (i < NMSG) {   // packed bucket build: msg slot i = fact*2 + parity
        const int g = i >> 1, p = i & 1;
        const float w = p ? bidir[g] : 1.0f;
        if (w != 0.0f) {
            const int ra0 = a0[g], ra1 = a1[g];
            const int X = p ? ra1 : ra0;       // through W1a
            const int Y = p ? ra0 : ra1;       // through W1c
            const int dest = p ? ra0 : ra1;    // destination node
            const int nid = ((g >> 12) << 10) + dest;
            const int slot = atomicAdd(&cnt[nid], 1);
            if (slot < CAP)
                idx32[nid * CAP + slot] = (uint)X | ((uint)Y << 10) | ((uint)pidx[g] << 20);
        }
    }
}

// ---------------------------------------------------------------------------
// node kernel (round-12 proven): per 16-node tile — bucket-gather G =
// sum gelu(Pa[X]+PE[pi]+Pc[Y]) fp32 regs -> bf16 swizzled LDS -> GEMM2 ->
// + c*b2 + pos_emb -> LayerNorm -> pooled.  512 blocks x 8 waves.
// ---------------------------------------------------------------------------
__global__ __launch_bounds__(512, 2) void node_kernel(
    const ushort* __restrict__ Pa, const ushort* __restrict__ Pc,
    const ushort* __restrict__ PE,
    const ushort* __restrict__ w2p, const float* __restrict__ b2,
    const float* __restrict__ pos_emb,
    const int* __restrict__ cnt, const uint* __restrict__ idx32,
    const float* __restrict__ ln_g, const float* __restrict__ ln_b,
    float* __restrict__ pooled)
{
    __shared__ uint4 h1g[512];        // 16 rows x 512 B, swizzled (8 KB)
    __shared__ float wsumS[16];
    __shared__ float aggf[16][132];   // padded fp32 agg tile (8.4 KB)
    __shared__ float red[8][128];     // pooled partials (4 KB)

    const int tid = threadIdx.x;
    const int wid = tid >> 6, lane = tid & 63;
    const int lq = lane >> 4, lr = lane & 15;
    const int nbase = blockIdx.x * 16;

    // ---- phase 1: G accumulate per node (wave handles 2 nodes) ----
    #pragma unroll
    for (int i = 0; i < 2; ++i) {
        const int n = wid * 2 + i;           // local node 0..15
        const int nid = nbase + n;
        int c = cnt[nid]; if (c > CAP) c = CAP;
        const uint* bucket = idx32 + nid * CAP;
        float G0 = 0.0f, G1 = 0.0f, G2 = 0.0f, G3 = 0.0f;
        for (int j = 0; j < c; ++j) {
            const uint e = bucket[j];
            const int X = e & 1023;
            const int Y = (e >> 10) & 1023;
            const int rpi = e >> 20;
            const uint2 ua = *(const uint2*)(Pa + X * 256 + lane * 4);
            const uint2 ub = *(const uint2*)(PE + rpi * 256 + lane * 4);
            const uint2 uc = *(const uint2*)(Pc + Y * 256 + lane * 4);
            const float h0 = bf2f(ua.x & 0xffffu) + bf2f(ub.x & 0xffffu) + bf2f(uc.x & 0xffffu);
            const float h1 = bf2f(ua.x >> 16)     + bf2f(ub.x >> 16)     + bf2f(uc.x >> 16);
            const float h2 = bf2f(ua.y & 0xffffu) + bf2f(ub.y & 0xffffu) + bf2f(uc.y & 0xffffu);
            const float h3 = bf2f(ua.y >> 16)     + bf2f(ub.y >> 16)     + bf2f(uc.y >> 16);
            G0 += gelu_fast(h0);
            G1 += gelu_fast(h1);
            G2 += gelu_fast(h2);
            G3 += gelu_fast(h3);
        }
        uint2 t;
        t.x = f2bf(G0) | (f2bf(G1) << 16);
        t.y = f2bf(G2) | (f2bf(G3) << 16);
        const int col = lane * 8;     // byte col within 512B row
        const int byteoff = n * 512 + ((((col >> 4)) ^ (n & 15)) << 4) + (col & 15);
        *(uint2*)((char*)h1g + byteoff) = t;
        if (lane == 0) wsumS[n] = (float)c;
    }
    __syncthreads();

    // ---- GEMM2 (node granularity): D[d][m], m = lr, d = wid*16 + lq*4+r ----
    f32x4 acc = (f32x4)0.0f;
    #pragma unroll
    for (int ks = 0; ks < 8; ++ks) {
        const int m = lr;
        const short8 hfrag = *(const short8*)((char*)h1g + m * 512 + ((((ks * 4 + lq)) ^ (m & 15)) << 4));
        const short8 wfrag = *(const short8*)(w2p + (wid * 8 + ks) * 512 + lr * 32 + lq * 8);
        acc = __builtin_amdgcn_mfma_f32_16x16x32_bf16(wfrag, hfrag, acc, 0, 0, 0);
    }

    // ---- epilogue: + wsum*b2 + pos_emb -> aggf LDS ----
    {
        const float wsm = wsumS[lr];
        const int s = (nbase + lr) & (SS - 1);
        const int d0 = wid * 16 + lq * 4;
        const float4 b24 = *(const float4*)(b2 + d0);
        const float4 pe4 = *(const float4*)(pos_emb + s * DD + d0);
        float4 o;
        o.x = __builtin_fmaf(wsm, b24.x, acc[0] + pe4.x);
        o.y = __builtin_fmaf(wsm, b24.y, acc[1] + pe4.y);
        o.z = __builtin_fmaf(wsm, b24.z, acc[2] + pe4.z);
        o.w = __builtin_fmaf(wsm, b24.w, acc[3] + pe4.w);
        *(float4*)&aggf[lr][d0] = o;
    }
    __syncthreads();

    // ---- LayerNorm + pool: wave handles its 2 nodes ----
    const float g0 = ln_g[lane], g1 = ln_g[lane + 64];
    const float bb0 = ln_b[lane], bb1 = ln_b[lane + 64];
    float p0 = 0.0f, p1 = 0.0f;
    #pragma unroll
    for (int i = 0; i < 2; ++i) {
        const int n = wid * 2 + i;
        const float h0 = aggf[n][lane];
        const float h1 = aggf[n][lane + 64];
        float sum = h0 + h1;
        #pragma unroll
        for (int o = 32; o > 0; o >>= 1) sum += __shfl_xor(sum, o);
        const float mu = sum * (1.0f / 128.0f);
        const float d0 = h0 - mu, d1 = h1 - mu;
        float sq = d0 * d0 + d1 * d1;
        #pragma unroll
        for (int o = 32; o > 0; o >>= 1) sq += __shfl_xor(sq, o);
        const float rstd = rsqrtf(sq * (1.0f / 128.0f) + 1e-5f);
        p0 += d0 * rstd * g0 + bb0;
        p1 += d1 * rstd * g1 + bb1;
    }
    red[wid][lane]      = p0;
    red[wid][lane + 64] = p1;
    __syncthreads();
    if (tid < 128) {
        float v = 0.0f;
        #pragma unroll
        for (int w = 0; w < 8; ++w) v += red[w][tid];
        const int b = nbase >> 10;
        atomicAdd(&pooled[b * DD + tid], v);
    }
}

// ---------------------------------------------------------------------------
// Latent head
// ---------------------------------------------------------------------------
__global__ __launch_bounds__(256) void head_kernel(
    const float* __restrict__ pooled,
    const float* __restrict__ lw1, const float* __restrict__ lb1,
    const float* __restrict__ lw2, const float* __restrict__ lb2,
    float* __restrict__ out)
{
    const int b = blockIdx.x;
    const int j = threadIdx.x;
    __shared__ float p[128];
    __shared__ float t1[256];
    if (j < 128) p[j] = pooled[b*DD + j] * (1.0f / (float)SS);
    __syncthreads();
    float acc = lb1[j];
    #pragma unroll 8
    for (int k = 0; k < 128; ++k) acc = __builtin_fmaf(p[k], lw1[k * 256 + j], acc);
    t1[j] = gelu_fast(acc);
    __syncthreads();
    float acc2 = lb2[j];
    #pragma unroll 8
    for (int k = 0; k < 256; ++k) acc2 = __builtin_fmaf(t1[k], lw2[k * 256 + j], acc2);
    out[b*DLL + j] = acc2;
}

extern "C" void kernel_launch(void* const* d_in, const int* in_sizes, int n_in,
                              void* d_out, int out_size, void* d_ws, size_t ws_size,
                              hipStream_t stream) {
    const int*   a0       = (const int*)d_in[0];
    const int*   a1       = (const int*)d_in[1];
    const int*   pidx     = (const int*)d_in[2];
    const float* bidir    = (const float*)d_in[3];
    const float* pos_emb  = (const float*)d_in[4];
    const float* pred_emb = (const float*)d_in[5];
    const float* w1       = (const float*)d_in[6];
    const float* b1       = (const float*)d_in[7];
    const float* w2       = (const float*)d_in[8];
    const float* b2       = (const float*)d_in[9];
    const float* ln_g     = (const float*)d_in[10];
    const float* ln_b     = (const float*)d_in[11];
    const float* lw1      = (const float*)d_in[12];
    const float* lb1      = (const float*)d_in[13];
    const float* lw2      = (const float*)d_in[14];
    const float* lb2      = (const float*)d_in[15];

    char* ws = (char*)d_ws;
    const size_t O_CNT  = 0;                                // 32 KB (int[NNODE])
    const size_t O_POOL = 32768;                            // 4 KB  (fp32[B*D])
    const size_t O_IDX  = O_POOL + 4096;                    // 1.18 MB (NNODE*CAP u32)
    const size_t O_W2P  = O_IDX + (size_t)NNODE * CAP * 4;  // 64 KB
    const size_t O_PA   = O_W2P + 65536;                    // 512 KB
    const size_t O_PC   = O_PA + 524288;                    // 512 KB
    const size_t O_PE   = O_PC + 524288;                    // 7 KB

    int*    cnt    = (int*)(ws + O_CNT);
    float*  pooled = (float*)(ws + O_POOL);
    uint*   idx32  = (uint*)(ws + O_IDX);
    ushort* w2p    = (ushort*)(ws + O_W2P);
    ushort* Pa     = (ushort*)(ws + O_PA);
    ushort* Pc     = (ushort*)(ws + O_PC);
    ushort* PE     = (ushort*)(ws + O_PE);

    zero_kernel<<<(NNODE + BB*DD + 255) / 256, 256, 0, stream>>>(cnt, pooled);
    prep_kernel<<<PREP_GRID, 256, 0, stream>>>(
        pos_emb, pred_emb, w1, b1, w2, a0, a1, pidx, bidir,
        Pa, Pc, PE, w2p, cnt, idx32);
    node_kernel<<<NNODE / 16, 512, 0, stream>>>(
        Pa, Pc, PE, w2p, b2, pos_emb, cnt, idx32, ln_g, ln_b, pooled);
    head_kernel<<<BB, 256, 0, stream>>>(pooled, lw1, lb1, lw2, lb2, (float*)d_out);
}

// Round 15
// 46.852 us; speedup vs baseline: 1.4370x; 1.0531x over previous
//
#include <hip/hip_runtime.h>
#include <hip/hip_bf16.h>

#define BB 8
#define FF 4096
#define SS 1024
#define DD 128
#define DLL 256
#define NF (BB*FF)     // 32768 facts
#define NMSG (2*NF)    // 65536 message slots
#define NNODE (BB*SS)  // 8192 (b,s) rows
#define CAP 36         // bucket capacity per node

typedef short  short8 __attribute__((ext_vector_type(8)));
typedef float  f32x4  __attribute__((ext_vector_type(4)));

__device__ __forceinline__ uint f2bf(float x) {
    uint u = __float_as_uint(x);
    return (u + 0x7fffu + ((u >> 16) & 1u)) >> 16;
}
__device__ __forceinline__ float bf2f(uint lo16) {
    return __uint_as_float(lo16 << 16);
}

// gelu(x) = 0.5x(1+erf(x/sqrt2)); erf via A&S 7.1.26, |err|<=1.5e-7, branchless.
__device__ __forceinline__ float gelu_fast(float x) {
    const float z = fabsf(x) * 0.70710678118654752440f;
    const float t = __builtin_amdgcn_rcpf(__builtin_fmaf(0.3275911f, z, 1.0f));
    float p = 1.061405429f;
    p = __builtin_fmaf(p, t, -1.453152027f);
    p = __builtin_fmaf(p, t, 1.421413741f);
    p = __builtin_fmaf(p, t, -0.284496736f);
    p = __builtin_fmaf(p, t, 0.254829592f);
    p *= t;
    const float e = __expf(-z * z);
    const float erfv = __builtin_fmaf(-p, e, 1.0f);
    return 0.5f * x * (1.0f + copysignf(erfv, x));
}

// ---------------------------------------------------------------------------
// Zero kernel: cnt[NNODE] + pooled[BB*DD]  (must precede prep's bucket build)
// ---------------------------------------------------------------------------
__global__ __launch_bounds__(256) void zero_kernel(int* __restrict__ cnt,
                                                   float* __restrict__ pooled)
{
    const int i = blockIdx.x * 256 + threadIdx.x;
    if (i < NNODE) { cnt[i] = 0; return; }
    const int j = i - NNODE;
    if (j < BB * DD) pooled[j] = 0.0f;
}

// ---------------------------------------------------------------------------
// Prep (round-14 proven): PA table GEMMs + 4-block LDS-staged PE,
// w2 frag-pack, packed bucket build.  Bucket entry = X | Y<<10 | rpi<<20.
// ---------------------------------------------------------------------------
#define N_W2 (256*128)
#define PA_BLOCKS 256                      // 4 s-rows per block
#define PE0       PA_BLOCKS                // 4 PE blocks, 64 j-cols each
#define FLAT0     (PA_BLOCKS + 4)
#define N_FLAT    (N_W2 + NMSG)
#define FLAT_BLOCKS ((N_FLAT + 255) / 256)  // 384
#define PREP_GRID (FLAT0 + FLAT_BLOCKS)

__global__ __launch_bounds__(256) void prep_kernel(
    const float* __restrict__ pos_emb, const float* __restrict__ pred_emb,
    const float* __restrict__ w1, const float* __restrict__ b1,
    const float* __restrict__ w2,
    const int* __restrict__ a0, const int* __restrict__ a1,
    const int* __restrict__ pidx, const float* __restrict__ bidir,
    ushort* __restrict__ Pa, ushort* __restrict__ Pc, ushort* __restrict__ PE,
    ushort* __restrict__ w2p, int* __restrict__ cnt, uint* __restrict__ idx32)
{
    const int blk = blockIdx.x;
    const int tid = threadIdx.x;

    if (blk < PA_BLOCKS) {
        __shared__ float ps[4][128];
        const int s0 = blk * 4;
        for (int q = tid; q < 512; q += 256) ps[q >> 7][q & 127] = pos_emb[s0 * 128 + q];
        __syncthreads();
        const int j = tid;
        float aa[4], ac[4];
        #pragma unroll
        for (int r = 0; r < 4; ++r) { aa[r] = 0.0f; ac[r] = 0.0f; }
        #pragma unroll 4
        for (int k = 0; k < 128; ++k) {
            const float wa = w1[k * 256 + j];
            const float wc = w1[(256 + k) * 256 + j];
            #pragma unroll
            for (int r = 0; r < 4; ++r) {
                aa[r] = __builtin_fmaf(ps[r][k], wa, aa[r]);
                ac[r] = __builtin_fmaf(ps[r][k], wc, ac[r]);
            }
        }
        #pragma unroll
        for (int r = 0; r < 4; ++r) {
            Pa[(s0 + r) * 256 + j] = (ushort)f2bf(aa[r]);
            Pc[(s0 + r) * 256 + j] = (ushort)f2bf(ac[r]);
        }
        return;
    }
    if (blk < FLAT0) {
        __shared__ float w1s[128][64];    // 32 KB
        __shared__ float prs[16][128];    // 8 KB (rows 14/15 zeroed)
        const int j0 = (blk - PE0) * 64;
        for (int q = tid; q < 128 * 64; q += 256) {
            const int k = q >> 6, jj = q & 63;
            w1s[k][jj] = w1[(128 + k) * 256 + j0 + jj];
        }
        for (int q = tid; q < 16 * 128; q += 256)
            prs[q >> 7][q & 127] = (q < 14 * 128) ? pred_emb[q] : 0.0f;
        __syncthreads();
        const int jl = tid & 63, rq = tid >> 6;
        float acc[4] = {0.0f, 0.0f, 0.0f, 0.0f};
        #pragma unroll 8
        for (int k = 0; k < 128; ++k) {
            const float wv = w1s[k][jl];
            #pragma unroll
            for (int i = 0; i < 4; ++i)
                acc[i] = __builtin_fmaf(prs[rq + 4 * i][k], wv, acc[i]);
        }
        const float bj = b1[j0 + jl];
        #pragma unroll
        for (int i = 0; i < 4; ++i) {
            const int r = rq + 4 * i;
            if (r < 14) PE[r * 256 + j0 + jl] = (ushort)f2bf(acc[i] + bj);
        }
        return;
    }
    int i = (blk - FLAT0) * 256 + tid;
    if (i < N_W2) {   // i = k*128 + d -> frag-packed for GEMM2 A operand
        const int k = i >> 7, d = i & 127;
        const int d0 = d >> 4, lr = d & 15, ks = k >> 5, lq = (k >> 3) & 3, e = k & 7;
        w2p[(d0 * 8 + ks) * 512 + lr * 32 + lq * 8 + e] = (ushort)f2bf(w2[i]);
        return;
    }
    i -= N_W2;
    if (i < NMSG) {   // packed bucket build: msg slot i = fact*2 + parity
        const int g = i >> 1, p = i & 1;
        const float w = p ? bidir[g] : 1.0f;
        if (w != 0.0f) {
            const int ra0 = a0[g], ra1 = a1[g];
            const int X = p ? ra1 : ra0;       // through W1a
            const int Y = p ? ra0 : ra1;       // through W1c
            const int dest = p ? ra0 : ra1;    // destination node
            const int nid = ((g >> 12) << 10) + dest;
            const int slot = atomicAdd(&cnt[nid], 1);
            if (slot < CAP)
                idx32[nid * CAP + slot] = (uint)X | ((uint)Y << 10) | ((uint)pidx[g] << 20);
        }
    }
}

// ---------------------------------------------------------------------------
// node kernel: 8 nodes per 512-thread block (1 node per wave), 1024 blocks,
// launch_bounds(512,8) -> 4 blocks/CU (32 waves/CU).  Phase-1 message loop is
// software-pipelined: next message's 3 gathers issue before current gelu.
// GEMM2 pads m to 16 (rows 8-15 garbage, outputs discarded).
// ---------------------------------------------------------------------------
__global__ __launch_bounds__(512, 8) void node_kernel(
    const ushort* __restrict__ Pa, const ushort* __restrict__ Pc,
    const ushort* __restrict__ PE,
    const ushort* __restrict__ w2p, const float* __restrict__ b2,
    const float* __restrict__ pos_emb,
    const int* __restrict__ cnt, const uint* __restrict__ idx32,
    const float* __restrict__ ln_g, const float* __restrict__ ln_b,
    float* __restrict__ pooled)
{
    __shared__ uint4 h1g[512];        // 16 rows x 512 B (rows 8-15 unused), 8 KB
    __shared__ float wsumS[8];
    __shared__ float aggf[8][132];    // padded fp32 agg tile (4.2 KB)
    __shared__ float red[8][128];     // pooled partials (4 KB)

    const int tid = threadIdx.x;
    const int wid = tid >> 6, lane = tid & 63;
    const int lq = lane >> 4, lr = lane & 15;
    const int nbase = blockIdx.x * 8;

    // ---- phase 1: one node per wave, software-pipelined message loop ----
    {
        const int nid = nbase + wid;
        int c = cnt[nid]; if (c > CAP) c = CAP;
        const uint* bucket = idx32 + nid * CAP;
        float G0 = 0.0f, G1 = 0.0f, G2 = 0.0f, G3 = 0.0f;
        if (c > 0) {
            uint e = bucket[0];
            uint2 ua = *(const uint2*)(Pa + (e & 1023) * 256 + lane * 4);
            uint2 ub = *(const uint2*)(PE + (e >> 20) * 256 + lane * 4);
            uint2 uc = *(const uint2*)(Pc + ((e >> 10) & 1023) * 256 + lane * 4);
            for (int j = 0; j < c; ++j) {
                // stage next message's gathers (redundant re-load on last iter)
                const uint en = bucket[(j + 1 < c) ? j + 1 : j];
                const uint2 ua_n = *(const uint2*)(Pa + (en & 1023) * 256 + lane * 4);
                const uint2 ub_n = *(const uint2*)(PE + (en >> 20) * 256 + lane * 4);
                const uint2 uc_n = *(const uint2*)(Pc + ((en >> 10) & 1023) * 256 + lane * 4);
                // compute current
                G0 += gelu_fast(bf2f(ua.x & 0xffffu) + bf2f(ub.x & 0xffffu) + bf2f(uc.x & 0xffffu));
                G1 += gelu_fast(bf2f(ua.x >> 16)     + bf2f(ub.x >> 16)     + bf2f(uc.x >> 16));
                G2 += gelu_fast(bf2f(ua.y & 0xffffu) + bf2f(ub.y & 0xffffu) + bf2f(uc.y & 0xffffu));
                G3 += gelu_fast(bf2f(ua.y >> 16)     + bf2f(ub.y >> 16)     + bf2f(uc.y >> 16));
                ua = ua_n; ub = ub_n; uc = uc_n;
            }
        }
        uint2 t;
        t.x = f2bf(G0) | (f2bf(G1) << 16);
        t.y = f2bf(G2) | (f2bf(G3) << 16);
        const int col = lane * 8;     // byte col within 512B row
        const int byteoff = wid * 512 + ((((col >> 4)) ^ (wid & 15)) << 4) + (col & 15);
        *(uint2*)((char*)h1g + byteoff) = t;
        if (lane == 0) wsumS[wid] = (float)c;
    }
    __syncthreads();

    // ---- GEMM2: D[d][m], m = lr (rows 0-7 valid), d = wid*16 + lq*4+r ----
    f32x4 acc = (f32x4)0.0f;
    #pragma unroll
    for (int ks = 0; ks < 8; ++ks) {
        const int m = lr;
        const short8 hfrag = *(const short8*)((char*)h1g + m * 512 + ((((ks * 4 + lq)) ^ (m & 15)) << 4));
        const short8 wfrag = *(const short8*)(w2p + (wid * 8 + ks) * 512 + lr * 32 + lq * 8);
        acc = __builtin_amdgcn_mfma_f32_16x16x32_bf16(wfrag, hfrag, acc, 0, 0, 0);
    }

    // ---- epilogue: + wsum*b2 + pos_emb -> aggf LDS (only m=lr<8 valid) ----
    if (lr < 8) {
        const float wsm = wsumS[lr];
        const int s = (nbase + lr) & (SS - 1);
        const int d0 = wid * 16 + lq * 4;
        const float4 b24 = *(const float4*)(b2 + d0);
        const float4 pe4 = *(const float4*)(pos_emb + s * DD + d0);
        float4 o;
        o.x = __builtin_fmaf(wsm, b24.x, acc[0] + pe4.x);
        o.y = __builtin_fmaf(wsm, b24.y, acc[1] + pe4.y);
        o.z = __builtin_fmaf(wsm, b24.z, acc[2] + pe4.z);
        o.w = __builtin_fmaf(wsm, b24.w, acc[3] + pe4.w);
        *(float4*)&aggf[lr][d0] = o;
    }
    __syncthreads();

    // ---- LayerNorm + pool: one node per wave ----
    {
        const float g0 = ln_g[lane], g1 = ln_g[lane + 64];
        const float bb0 = ln_b[lane], bb1 = ln_b[lane + 64];
        const float h0 = aggf[wid][lane];
        const float h1 = aggf[wid][lane + 64];
        float sum = h0 + h1;
        #pragma unroll
        for (int o = 32; o > 0; o >>= 1) sum += __shfl_xor(sum, o);
        const float mu = sum * (1.0f / 128.0f);
        const float d0 = h0 - mu, d1 = h1 - mu;
        float sq = d0 * d0 + d1 * d1;
        #pragma unroll
        for (int o = 32; o > 0; o >>= 1) sq += __shfl_xor(sq, o);
        const float rstd = rsqrtf(sq * (1.0f / 128.0f) + 1e-5f);
        red[wid][lane]      = d0 * rstd * g0 + bb0;
        red[wid][lane + 64] = d1 * rstd * g1 + bb1;
    }
    __syncthreads();
    if (tid < 128) {
        float v = 0.0f;
        #pragma unroll
        for (int w = 0; w < 8; ++w) v += red[w][tid];
        const int b = nbase >> 10;
        atomicAdd(&pooled[b * DD + tid], v);
    }
}

// ---------------------------------------------------------------------------
// Latent head
// ---------------------------------------------------------------------------
__global__ __launch_bounds__(256) void head_kernel(
    const float* __restrict__ pooled,
    const float* __restrict__ lw1, const float* __restrict__ lb1,
    const float* __restrict__ lw2, const float* __restrict__ lb2,
    float* __restrict__ out)
{
    const int b = blockIdx.x;
    const int j = threadIdx.x;
    __shared__ float p[128];
    __shared__ float t1[256];
    if (j < 128) p[j] = pooled[b*DD + j] * (1.0f / (float)SS);
    __syncthreads();
    float acc = lb1[j];
    #pragma unroll 8
    for (int k = 0; k < 128; ++k) acc = __builtin_fmaf(p[k], lw1[k * 256 + j], acc);
    t1[j] = gelu_fast(acc);
    __syncthreads();
    float acc2 = lb2[j];
    #pragma unroll 8
    for (int k = 0; k < 256; ++k) acc2 = __builtin_fmaf(t1[k], lw2[k * 256 + j], acc2);
    out[b*DLL + j] = acc2;
}

extern "C" void kernel_launch(void* const* d_in, const int* in_sizes, int n_in,
                              void* d_out, int out_size, void* d_ws, size_t ws_size,
                              hipStream_t stream) {
    const int*   a0       = (const int*)d_in[0];
    const int*   a1       = (const int*)d_in[1];
    const int*   pidx     = (const int*)d_in[2];
    const float* bidir    = (const float*)d_in[3];
    const float* pos_emb  = (const float*)d_in[4];
    const float* pred_emb = (const float*)d_in[5];
    const float* w1       = (const float*)d_in[6];
    const float* b1       = (const float*)d_in[7];
    const float* w2       = (const float*)d_in[8];
    const float* b2       = (const float*)d_in[9];
    const float* ln_g     = (const float*)d_in[10];
    const float* ln_b     = (const float*)d_in[11];
    const float* lw1      = (const float*)d_in[12];
    const float* lb1      = (const float*)d_in[13];
    const float* lw2      = (const float*)d_in[14];
    const float* lb2      = (const float*)d_in[15];

    char* ws = (char*)d_ws;
    const size_t O_CNT  = 0;                                // 32 KB (int[NNODE])
    const size_t O_POOL = 32768;                            // 4 KB  (fp32[B*D])
    const size_t O_IDX  = O_POOL + 4096;                    // 1.18 MB (NNODE*CAP u32)
    const size_t O_W2P  = O_IDX + (size_t)NNODE * CAP * 4;  // 64 KB
    const size_t O_PA   = O_W2P + 65536;                    // 512 KB
    const size_t O_PC   = O_PA + 524288;                    // 512 KB
    const size_t O_PE   = O_PC + 524288;                    // 7 KB

    int*    cnt    = (int*)(ws + O_CNT);
    float*  pooled = (float*)(ws + O_POOL);
    uint*   idx32  = (uint*)(ws + O_IDX);
    ushort* w2p    = (ushort*)(ws + O_W2P);
    ushort* Pa     = (ushort*)(ws + O_PA);
    ushort* Pc     = (ushort*)(ws + O_PC);
    ushort* PE     = (ushort*)(ws + O_PE);

    zero_kernel<<<(NNODE + BB*DD + 255) / 256, 256, 0, stream>>>(cnt, pooled);
    prep_kernel<<<PREP_GRID, 256, 0, stream>>>(
        pos_emb, pred_emb, w1, b1, w2, a0, a1, pidx, bidir,
        Pa, Pc, PE, w2p, cnt, idx32);
    node_kernel<<<NNODE / 8, 512, 0, stream>>>(
        Pa, Pc, PE, w2p, b2, pos_emb, cnt, idx32, ln_g, ln_b, pooled);
    head_kernel<<<BB, 256, 0, stream>>>(pooled, lw1, lb1, lw2, lb2, (float*)d_out);
}

// Round 16
// 44.260 us; speedup vs baseline: 1.5212x; 1.0586x over previous
//
#include <hip/hip_runtime.h>
#include <hip/hip_bf16.h>

#define BB 8
#define FF 4096
#define SS 1024
#define DD 128
#define DLL 256
#define NF (BB*FF)     // 32768 facts
#define NMSG (2*NF)    // 65536 message slots
#define NNODE (BB*SS)  // 8192 (b,s) rows
#define CAP 36         // bucket capacity per node

typedef short  short8 __attribute__((ext_vector_type(8)));
typedef float  f32x4  __attribute__((ext_vector_type(4)));

__device__ __forceinline__ uint f2bf(float x) {
    uint u = __float_as_uint(x);
    return (u + 0x7fffu + ((u >> 16) & 1u)) >> 16;
}
__device__ __forceinline__ float bf2f(uint lo16) {
    return __uint_as_float(lo16 << 16);
}

// gelu(x) = 0.5x(1+erf(x/sqrt2)); erf via A&S 7.1.26, |err|<=1.5e-7, branchless.
__device__ __forceinline__ float gelu_fast(float x) {
    const float z = fabsf(x) * 0.70710678118654752440f;
    const float t = __builtin_amdgcn_rcpf(__builtin_fmaf(0.3275911f, z, 1.0f));
    float p = 1.061405429f;
    p = __builtin_fmaf(p, t, -1.453152027f);
    p = __builtin_fmaf(p, t, 1.421413741f);
    p = __builtin_fmaf(p, t, -0.284496736f);
    p = __builtin_fmaf(p, t, 0.254829592f);
    p *= t;
    const float e = __expf(-z * z);
    const float erfv = __builtin_fmaf(-p, e, 1.0f);
    return 0.5f * x * (1.0f + copysignf(erfv, x));
}

// ---------------------------------------------------------------------------
// Zero kernel: cnt[NNODE] + pooled[BB*DD]
// ---------------------------------------------------------------------------
__global__ __launch_bounds__(256) void zero_kernel(int* __restrict__ cnt,
                                                   float* __restrict__ pooled)
{
    const int i = blockIdx.x * 256 + threadIdx.x;
    if (i < NNODE) { cnt[i] = 0; return; }
    const int j = i - NNODE;
    if (j < BB * DD) pooled[j] = 0.0f;
}

// ---------------------------------------------------------------------------
// Prep (round-14 proven): PA table GEMMs + 4-block LDS-staged PE,
// w2 frag-pack, packed bucket build.  Bucket entry = X | Y<<10 | rpi<<20.
// ---------------------------------------------------------------------------
#define N_W2 (256*128)
#define PA_BLOCKS 256                      // 4 s-rows per block
#define PE0       PA_BLOCKS                // 4 PE blocks, 64 j-cols each
#define FLAT0     (PA_BLOCKS + 4)
#define N_FLAT    (N_W2 + NMSG)
#define FLAT_BLOCKS ((N_FLAT + 255) / 256)  // 384
#define PREP_GRID (FLAT0 + FLAT_BLOCKS)

__global__ __launch_bounds__(256) void prep_kernel(
    const float* __restrict__ pos_emb, const float* __restrict__ pred_emb,
    const float* __restrict__ w1, const float* __restrict__ b1,
    const float* __restrict__ w2,
    const int* __restrict__ a0, const int* __restrict__ a1,
    const int* __restrict__ pidx, const float* __restrict__ bidir,
    ushort* __restrict__ Pa, ushort* __restrict__ Pc, ushort* __restrict__ PE,
    ushort* __restrict__ w2p, int* __restrict__ cnt, uint* __restrict__ idx32)
{
    const int blk = blockIdx.x;
    const int tid = threadIdx.x;

    if (blk < PA_BLOCKS) {
        __shared__ float ps[4][128];
        const int s0 = blk * 4;
        for (int q = tid; q < 512; q += 256) ps[q >> 7][q & 127] = pos_emb[s0 * 128 + q];
        __syncthreads();
        const int j = tid;
        float aa[4], ac[4];
        #pragma unroll
        for (int r = 0; r < 4; ++r) { aa[r] = 0.0f; ac[r] = 0.0f; }
        #pragma unroll 4
        for (int k = 0; k < 128; ++k) {
            const float wa = w1[k * 256 + j];
            const float wc = w1[(256 + k) * 256 + j];
            #pragma unroll
            for (int r = 0; r < 4; ++r) {
                aa[r] = __builtin_fmaf(ps[r][k], wa, aa[r]);
                ac[r] = __builtin_fmaf(ps[r][k], wc, ac[r]);
            }
        }
        #pragma unroll
        for (int r = 0; r < 4; ++r) {
            Pa[(s0 + r) * 256 + j] = (ushort)f2bf(aa[r]);
            Pc[(s0 + r) * 256 + j] = (ushort)f2bf(ac[r]);
        }
        return;
    }
    if (blk < FLAT0) {
        __shared__ float w1s[128][64];    // 32 KB
        __shared__ float prs[16][128];    // 8 KB (rows 14/15 zeroed)
        const int j0 = (blk - PE0) * 64;
        for (int q = tid; q < 128 * 64; q += 256) {
            const int k = q >> 6, jj = q & 63;
            w1s[k][jj] = w1[(128 + k) * 256 + j0 + jj];
        }
        for (int q = tid; q < 16 * 128; q += 256)
            prs[q >> 7][q & 127] = (q < 14 * 128) ? pred_emb[q] : 0.0f;
        __syncthreads();
        const int jl = tid & 63, rq = tid >> 6;
        float acc[4] = {0.0f, 0.0f, 0.0f, 0.0f};
        #pragma unroll 8
        for (int k = 0; k < 128; ++k) {
            const float wv = w1s[k][jl];
            #pragma unroll
            for (int i = 0; i < 4; ++i)
                acc[i] = __builtin_fmaf(prs[rq + 4 * i][k], wv, acc[i]);
        }
        const float bj = b1[j0 + jl];
        #pragma unroll
        for (int i = 0; i < 4; ++i) {
            const int r = rq + 4 * i;
            if (r < 14) PE[r * 256 + j0 + jl] = (ushort)f2bf(acc[i] + bj);
        }
        return;
    }
    int i = (blk - FLAT0) * 256 + tid;
    if (i < N_W2) {   // i = k*128 + d -> frag-packed for GEMM2 A operand
        const int k = i >> 7, d = i & 127;
        const int d0 = d >> 4, lr = d & 15, ks = k >> 5, lq = (k >> 3) & 3, e = k & 7;
        w2p[(d0 * 8 + ks) * 512 + lr * 32 + lq * 8 + e] = (ushort)f2bf(w2[i]);
        return;
    }
    i -= N_W2;
    if (i < NMSG) {   // packed bucket build: msg slot i = fact*2 + parity
        const int g = i >> 1, p = i & 1;
        const float w = p ? bidir[g] : 1.0f;
        if (w != 0.0f) {
            const int ra0 = a0[g], ra1 = a1[g];
            const int X = p ? ra1 : ra0;       // through W1a
            const int Y = p ? ra0 : ra1;       // through W1c
            const int dest = p ? ra0 : ra1;    // destination node
            const int nid = ((g >> 12) << 10) + dest;
            const int slot = atomicAdd(&cnt[nid], 1);
            if (slot < CAP)
                idx32[nid * CAP + slot] = (uint)X | ((uint)Y << 10) | ((uint)pidx[g] << 20);
        }
    }
}

// ---------------------------------------------------------------------------
// node kernel (r13 structure + r15 prefetch): 16 nodes per 1024-thread block
// (1 node per wave), 512 blocks, launch_bounds(1024,4) -> 128-VGPR cap (no
// spill for the ~60-reg prefetch pipeline).  Full 16-row GEMM2 (no waste).
// ---------------------------------------------------------------------------
__global__ __launch_bounds__(1024, 4) void node_kernel(
    const ushort* __restrict__ Pa, const ushort* __restrict__ Pc,
    const ushort* __restrict__ PE,
    const ushort* __restrict__ w2p, const float* __restrict__ b2,
    const float* __restrict__ pos_emb,
    const int* __restrict__ cnt, const uint* __restrict__ idx32,
    const float* __restrict__ ln_g, const float* __restrict__ ln_b,
    float* __restrict__ pooled)
{
    __shared__ uint4 h1g[512];        // 16 rows x 512 B, swizzled (8 KB)
    __shared__ float wsumS[16];
    __shared__ float aggf[16][132];   // padded fp32 agg tile (8.4 KB)
    __shared__ float red[16][128];    // pooled partials (8 KB)

    const int tid = threadIdx.x;
    const int wid = tid >> 6, lane = tid & 63;
    const int lq = lane >> 4, lr = lane & 15;
    const int nbase = blockIdx.x * 16;

    // ---- phase 1: one node per wave, software-pipelined message loop ----
    {
        const int nid = nbase + wid;
        int c = cnt[nid]; if (c > CAP) c = CAP;
        const uint* bucket = idx32 + nid * CAP;
        float G0 = 0.0f, G1 = 0.0f, G2 = 0.0f, G3 = 0.0f;
        if (c > 0) {
            uint e = bucket[0];
            uint2 ua = *(const uint2*)(Pa + (e & 1023) * 256 + lane * 4);
            uint2 ub = *(const uint2*)(PE + (e >> 20) * 256 + lane * 4);
            uint2 uc = *(const uint2*)(Pc + ((e >> 10) & 1023) * 256 + lane * 4);
            for (int j = 0; j < c; ++j) {
                const uint en = bucket[(j + 1 < c) ? j + 1 : j];
                const uint2 ua_n = *(const uint2*)(Pa + (en & 1023) * 256 + lane * 4);
                const uint2 ub_n = *(const uint2*)(PE + (en >> 20) * 256 + lane * 4);
                const uint2 uc_n = *(const uint2*)(Pc + ((en >> 10) & 1023) * 256 + lane * 4);
                G0 += gelu_fast(bf2f(ua.x & 0xffffu) + bf2f(ub.x & 0xffffu) + bf2f(uc.x & 0xffffu));
                G1 += gelu_fast(bf2f(ua.x >> 16)     + bf2f(ub.x >> 16)     + bf2f(uc.x >> 16));
                G2 += gelu_fast(bf2f(ua.y & 0xffffu) + bf2f(ub.y & 0xffffu) + bf2f(uc.y & 0xffffu));
                G3 += gelu_fast(bf2f(ua.y >> 16)     + bf2f(ub.y >> 16)     + bf2f(uc.y >> 16));
                ua = ua_n; ub = ub_n; uc = uc_n;
            }
        }
        uint2 t;
        t.x = f2bf(G0) | (f2bf(G1) << 16);
        t.y = f2bf(G2) | (f2bf(G3) << 16);
        const int col = lane * 8;     // byte col within 512B row
        const int byteoff = wid * 512 + ((((col >> 4)) ^ (wid & 15)) << 4) + (col & 15);
        *(uint2*)((char*)h1g + byteoff) = t;
        if (lane == 0) wsumS[wid] = (float)c;
    }
    __syncthreads();

    // ---- GEMM2 (waves 0-7): D[d][m], m = lr (all 16 valid), d = wid*16+lq*4+r ----
    if (wid < 8) {
        f32x4 acc = (f32x4)0.0f;
        #pragma unroll
        for (int ks = 0; ks < 8; ++ks) {
            const int m = lr;
            const short8 hfrag = *(const short8*)((char*)h1g + m * 512 + ((((ks * 4 + lq)) ^ (m & 15)) << 4));
            const short8 wfrag = *(const short8*)(w2p + (wid * 8 + ks) * 512 + lr * 32 + lq * 8);
            acc = __builtin_amdgcn_mfma_f32_16x16x32_bf16(wfrag, hfrag, acc, 0, 0, 0);
        }
        // epilogue: + wsum*b2 + pos_emb -> aggf LDS
        const float wsm = wsumS[lr];
        const int s = (nbase + lr) & (SS - 1);
        const int d0 = wid * 16 + lq * 4;
        const float4 b24 = *(const float4*)(b2 + d0);
        const float4 pe4 = *(const float4*)(pos_emb + s * DD + d0);
        float4 o;
        o.x = __builtin_fmaf(wsm, b24.x, acc[0] + pe4.x);
        o.y = __builtin_fmaf(wsm, b24.y, acc[1] + pe4.y);
        o.z = __builtin_fmaf(wsm, b24.z, acc[2] + pe4.z);
        o.w = __builtin_fmaf(wsm, b24.w, acc[3] + pe4.w);
        *(float4*)&aggf[lr][d0] = o;
    }
    __syncthreads();

    // ---- LayerNorm + pool: one node per wave (all 16 waves) ----
    {
        const float g0 = ln_g[lane], g1 = ln_g[lane + 64];
        const float bb0 = ln_b[lane], bb1 = ln_b[lane + 64];
        const float h0 = aggf[wid][lane];
        const float h1 = aggf[wid][lane + 64];
        float sum = h0 + h1;
        #pragma unroll
        for (int o = 32; o > 0; o >>= 1) sum += __shfl_xor(sum, o);
        const float mu = sum * (1.0f / 128.0f);
        const float d0 = h0 - mu, d1 = h1 - mu;
        float sq = d0 * d0 + d1 * d1;
        #pragma unroll
        for (int o = 32; o > 0; o >>= 1) sq += __shfl_xor(sq, o);
        const float rstd = rsqrtf(sq * (1.0f / 128.0f) + 1e-5f);
        red[wid][lane]      = d0 * rstd * g0 + bb0;
        red[wid][lane + 64] = d1 * rstd * g1 + bb1;
    }
    __syncthreads();
    if (tid < 128) {
        float v = 0.0f;
        #pragma unroll
        for (int w = 0; w < 16; ++w) v += red[w][tid];
        const int b = nbase >> 10;
        atomicAdd(&pooled[b * DD + tid], v);
    }
}

// ---------------------------------------------------------------------------
// Latent head
// ---------------------------------------------------------------------------
__global__ __launch_bounds__(256) void head_kernel(
    const float* __restrict__ pooled,
    const float* __restrict__ lw1, const float* __restrict__ lb1,
    const float* __restrict__ lw2, const float* __restrict__ lb2,
    float* __restrict__ out)
{
    const int b = blockIdx.x;
    const int j = threadIdx.x;
    __shared__ float p[128];
    __shared__ float t1[256];
    if (j < 128) p[j] = pooled[b*DD + j] * (1.0f / (float)SS);
    __syncthreads();
    float acc = lb1[j];
    #pragma unroll 8
    for (int k = 0; k < 128; ++k) acc = __builtin_fmaf(p[k], lw1[k * 256 + j], acc);
    t1[j] = gelu_fast(acc);
    __syncthreads();
    float acc2 = lb2[j];
    #pragma unroll 8
    for (int k = 0; k < 256; ++k) acc2 = __builtin_fmaf(t1[k], lw2[k * 256 + j], acc2);
    out[b*DLL + j] = acc2;
}

extern "C" void kernel_launch(void* const* d_in, const int* in_sizes, int n_in,
                              void* d_out, int out_size, void* d_ws, size_t ws_size,
                              hipStream_t stream) {
    const int*   a0       = (const int*)d_in[0];
    const int*   a1       = (const int*)d_in[1];
    const int*   pidx     = (const int*)d_in[2];
    const float* bidir    = (const float*)d_in[3];
    const float* pos_emb  = (const float*)d_in[4];
    const float* pred_emb = (const float*)d_in[5];
    const float* w1       = (const float*)d_in[6];
    const float* b1       = (const float*)d_in[7];
    const float* w2       = (const float*)d_in[8];
    const float* b2       = (const float*)d_in[9];
    const float* ln_g     = (const float*)d_in[10];
    const float* ln_b     = (const float*)d_in[11];
    const float* lw1      = (const float*)d_in[12];
    const float* lb1      = (const float*)d_in[13];
    const float* lw2      = (const float*)d_in[14];
    const float* lb2      = (const float*)d_in[15];

    char* ws = (char*)d_ws;
    const size_t O_CNT  = 0;                                // 32 KB (int[NNODE])
    const size_t O_POOL = 32768;                            // 4 KB  (fp32[B*D])
    const size_t O_IDX  = O_POOL + 4096;                    // 1.18 MB (NNODE*CAP u32)
    const size_t O_W2P  = O_IDX + (size_t)NNODE * CAP * 4;  // 64 KB
    const size_t O_PA   = O_W2P + 65536;                    // 512 KB
    const size_t O_PC   = O_PA + 524288;                    // 512 KB
    const size_t O_PE   = O_PC + 524288;                    // 7 KB

    int*    cnt    = (int*)(ws + O_CNT);
    float*  pooled = (float*)(ws + O_POOL);
    uint*   idx32  = (uint*)(ws + O_IDX);
    ushort* w2p    = (ushort*)(ws + O_W2P);
    ushort* Pa     = (ushort*)(ws + O_PA);
    ushort* Pc     = (ushort*)(ws + O_PC);
    ushort* PE     = (ushort*)(ws + O_PE);

    zero_kernel<<<(NNODE + BB*DD + 255) / 256, 256, 0, stream>>>(cnt, pooled);
    prep_kernel<<<PREP_GRID, 256, 0, stream>>>(
        pos_emb, pred_emb, w1, b1, w2, a0, a1, pidx, bidir,
        Pa, Pc, PE, w2p, cnt, idx32);
    node_kernel<<<NNODE / 16, 1024, 0, stream>>>(
        Pa, Pc, PE, w2p, b2, pos_emb, cnt, idx32, ln_g, ln_b, pooled);
    head_kernel<<<BB, 256, 0, stream>>>(pooled, lw1, lb1, lw2, lb2, (float*)d_out);
}